// Round 1
// baseline (1029.166 us; speedup 1.0000x reference)
//
#include <hip/hip_runtime.h>

#define NN 50000
#define DINF 128
#define DHID 128
#define DOUTF 64

// ---- degree histogram (float atomic counts are exact up to 2^24) ----
__global__ void deg_count_kernel(const int* __restrict__ idx, float* __restrict__ deg, int ne) {
    int i = blockIdx.x * 256 + threadIdx.x;
    if (i < ne) atomicAdd(&deg[idx[i]], 1.0f);
}

__global__ void rsqrt_kernel(float* __restrict__ deg, int n) {
    int i = blockIdx.x * 256 + threadIdx.x;
    if (i < n) deg[i] = rsqrtf(fmaxf(deg[i], 1.0f));
}

// ---- dense GEMM  Y[n,DOUT] = X[n,DIN] @ W[DIN,DOUT]  (f32 vector ALU) ----
// block = 256 threads; each thread computes 4 rows x 4 cols.
template<int DIN, int DOUT>
__global__ void gemm_kernel(const float* __restrict__ X, const float* __restrict__ W,
                            float* __restrict__ Y, int n) {
    constexpr int CG = DOUT / 4;        // col groups per row
    constexpr int RG = 256 / CG;        // row groups per block
    constexpr int BR = RG * 4;          // rows per block
    const int tc = threadIdx.x % CG;
    const int tr = threadIdx.x / CG;
    const int row0 = blockIdx.x * BR + tr * 4;
    const int c0 = tc * 4;

    float4 acc[4];
    #pragma unroll
    for (int r = 0; r < 4; ++r) acc[r] = make_float4(0.f, 0.f, 0.f, 0.f);

    for (int k = 0; k < DIN; k += 4) {
        float4 w0 = *(const float4*)(W + (size_t)(k + 0) * DOUT + c0);
        float4 w1 = *(const float4*)(W + (size_t)(k + 1) * DOUT + c0);
        float4 w2 = *(const float4*)(W + (size_t)(k + 2) * DOUT + c0);
        float4 w3 = *(const float4*)(W + (size_t)(k + 3) * DOUT + c0);
        #pragma unroll
        for (int r = 0; r < 4; ++r) {
            int row = row0 + r;
            if (row < n) {
                float4 xv = *(const float4*)(X + (size_t)row * DIN + k);
                acc[r].x += xv.x * w0.x + xv.y * w1.x + xv.z * w2.x + xv.w * w3.x;
                acc[r].y += xv.x * w0.y + xv.y * w1.y + xv.z * w2.y + xv.w * w3.y;
                acc[r].z += xv.x * w0.z + xv.y * w1.z + xv.z * w2.z + xv.w * w3.z;
                acc[r].w += xv.x * w0.w + xv.y * w1.w + xv.z * w2.w + xv.w * w3.w;
            }
        }
    }
    #pragma unroll
    for (int r = 0; r < 4; ++r) {
        int row = row0 + r;
        if (row < n) *(float4*)(Y + (size_t)row * DOUT + c0) = acc[r];
    }
}

// ---- edge scatter: acc[dst] += attn[ai] * rs_in[dst] * rs_out[src] * V[src] ----
// one wave (64 lanes) per edge
template<int D>
__global__ void scatter_kernel(const float* __restrict__ V, const int* __restrict__ src,
                               const int* __restrict__ dst, const float* __restrict__ rs_out,
                               const float* __restrict__ rs_in, const float* __restrict__ attn,
                               int ai, float* __restrict__ acc, int ne) {
    int gw = (blockIdx.x * 256 + threadIdx.x) >> 6;
    int lane = threadIdx.x & 63;
    if (gw >= ne) return;
    int s = src[gw];
    int d = dst[gw];
    float w = attn[ai] * rs_in[d] * rs_out[s];
    const float* vp = V + (size_t)s * D;
    float* ap = acc + (size_t)d * D;
    #pragma unroll
    for (int c = lane; c < D; c += 64)
        atomicAdd(ap + c, w * vp[c]);
}

// ---- out = acc + (attn0+attn1) * bias  (row-broadcast bias) ----
template<int D>
__global__ void bias_combine_kernel(const float* __restrict__ acc, const float* __restrict__ bias,
                                    const float* __restrict__ attn, float* __restrict__ out, int n) {
    int i = blockIdx.x * 256 + threadIdx.x;
    int total = n * (D / 4);
    if (i >= total) return;
    float s = attn[0] + attn[1];
    float4 a = ((const float4*)acc)[i];
    float4 b = ((const float4*)bias)[i % (D / 4)];
    float4 o = make_float4(a.x + s * b.x, a.y + s * b.y, a.z + s * b.z, a.w + s * b.w);
    ((float4*)out)[i] = o;
}

extern "C" void kernel_launch(void* const* d_in, const int* in_sizes, int n_in,
                              void* d_out, int out_size, void* d_ws, size_t ws_size,
                              hipStream_t stream) {
    const float* feat = (const float*)d_in[0];
    const int* src1   = (const int*)d_in[1];
    const int* dst1   = (const int*)d_in[2];
    const int* src2   = (const int*)d_in[3];
    const int* dst2   = (const int*)d_in[4];
    const float* attn = (const float*)d_in[5];
    const float* W1   = (const float*)d_in[6];
    const float* b1   = (const float*)d_in[7];
    const float* W2   = (const float*)d_in[8];
    const float* b2   = (const float*)d_in[9];
    float* out = (float*)d_out;

    const int N  = in_sizes[0] / DINF;   // 50000
    const int NE = in_sizes[1];          // 600000

    // workspace layout (floats): A[N*128] | B[N*128] | C[N*64] | rs[4*N]
    float* ws = (float*)d_ws;
    float* A  = ws;
    float* B  = A + (size_t)N * DHID;
    float* C  = B + (size_t)N * DHID;
    float* rs = C + (size_t)N * DOUTF;
    float* rs1o = rs;
    float* rs1i = rs + N;
    float* rs2o = rs + 2 * (size_t)N;
    float* rs2i = rs + 3 * (size_t)N;

    hipMemsetAsync(rs, 0, sizeof(float) * 4 * (size_t)N, stream);
    hipMemsetAsync(B, 0, sizeof(float) * (size_t)N * DHID, stream);
    hipMemsetAsync(C, 0, sizeof(float) * (size_t)N * DOUTF, stream);

    int eb = (NE + 255) / 256;
    deg_count_kernel<<<eb, 256, 0, stream>>>(src1, rs1o, NE);
    deg_count_kernel<<<eb, 256, 0, stream>>>(dst1, rs1i, NE);
    deg_count_kernel<<<eb, 256, 0, stream>>>(src2, rs2o, NE);
    deg_count_kernel<<<eb, 256, 0, stream>>>(dst2, rs2i, NE);
    rsqrt_kernel<<<(4 * N + 255) / 256, 256, 0, stream>>>(rs, 4 * N);

    // layer 1: XW1 -> A
    gemm_kernel<DINF, DHID><<<(N + 31) / 32, 256, 0, stream>>>(feat, W1, A, N);

    // scatter both graphs into single accumulator B (edge weight carries attn + norms)
    int sb = (NE + 3) / 4;  // 4 waves / block, 1 edge / wave
    scatter_kernel<DHID><<<sb, 256, 0, stream>>>(A, src1, dst1, rs1o, rs1i, attn, 0, B, NE);
    scatter_kernel<DHID><<<sb, 256, 0, stream>>>(A, src2, dst2, rs2o, rs2i, attn, 1, B, NE);

    // x1 = B + (a0+a1)*b1 -> A
    bias_combine_kernel<DHID><<<((N * (DHID / 4)) + 255) / 256, 256, 0, stream>>>(B, b1, attn, A, N);

    // layer 2: X1W2 -> B
    gemm_kernel<DHID, DOUTF><<<(N + 63) / 64, 256, 0, stream>>>(A, W2, B, N);

    scatter_kernel<DOUTF><<<sb, 256, 0, stream>>>(B, src1, dst1, rs1o, rs1i, attn, 0, C, NE);
    scatter_kernel<DOUTF><<<sb, 256, 0, stream>>>(B, src2, dst2, rs2o, rs2i, attn, 1, C, NE);

    // out = C + (a0+a1)*b2
    bias_combine_kernel<DOUTF><<<((N * (DOUTF / 4)) + 255) / 256, 256, 0, stream>>>(C, b2, attn, out, N);
}

// Round 2
// 614.116 us; speedup vs baseline: 1.6758x; 1.6758x over previous
//
#include <hip/hip_runtime.h>

#define DINF 128
#define DHID 128
#define DOUTF 64

// ---- integer degree histogram ----
__global__ void deg_count_kernel(const int* __restrict__ idx, int* __restrict__ deg, int ne) {
    int i = blockIdx.x * 256 + threadIdx.x;
    if (i < ne) atomicAdd(&deg[idx[i]], 1);
}

// ---- rs = rsqrt(max(deg,1)) for all 4 degree arrays at once ----
__global__ void rsqrt_kernel(const int* __restrict__ deg, float* __restrict__ rs, int n) {
    int i = blockIdx.x * 256 + threadIdx.x;
    if (i < n) rs[i] = rsqrtf(fmaxf((float)deg[i], 1.0f));
}

// ---- single-block exclusive scan of combined in-degree (d1i+d2i) -> offs, cursor ----
__global__ void scan_kernel(const int* __restrict__ d1i, const int* __restrict__ d2i,
                            int* __restrict__ offs, int* __restrict__ cursor, int n) {
    __shared__ int sums[256];
    __shared__ int pref[257];
    int t = threadIdx.x;
    int chunk = (n + 255) / 256;
    int lo = t * chunk;
    int hi = lo + chunk < n ? lo + chunk : n;
    int s = 0;
    for (int i = lo; i < hi; ++i) s += d1i[i] + d2i[i];
    sums[t] = s;
    __syncthreads();
    if (t == 0) {
        pref[0] = 0;
        for (int i = 0; i < 256; ++i) pref[i + 1] = pref[i] + sums[i];
    }
    __syncthreads();
    int run = pref[t];
    for (int i = lo; i < hi; ++i) {
        offs[i] = run;
        cursor[i] = run;
        run += d1i[i] + d2i[i];
    }
    if (t == 255) offs[n] = run;
}

// ---- CSR fill: per edge, place src index + folded weight into dst bucket ----
__global__ void fill_kernel(const int* __restrict__ src, const int* __restrict__ dst,
                            const float* __restrict__ rs_out, const float* __restrict__ rs_in,
                            const float* __restrict__ attn, int ai,
                            int* __restrict__ cursor, int* __restrict__ csr_src,
                            float* __restrict__ csr_w, int ne) {
    int i = blockIdx.x * 256 + threadIdx.x;
    if (i >= ne) return;
    int s = src[i];
    int d = dst[i];
    int pos = atomicAdd(&cursor[d], 1);
    csr_src[pos] = s;
    csr_w[pos] = attn[ai] * rs_in[d] * rs_out[s];
}

// ---- dense GEMM  Y[n,DOUT] = X[n,DIN] @ W[DIN,DOUT]  (f32 vector ALU) ----
template<int DIN, int DOUT>
__global__ void gemm_kernel(const float* __restrict__ X, const float* __restrict__ W,
                            float* __restrict__ Y, int n) {
    constexpr int CG = DOUT / 4;        // col groups per row
    constexpr int RG = 256 / CG;        // row groups per block
    constexpr int BR = RG * 4;          // rows per block
    const int tc = threadIdx.x % CG;
    const int tr = threadIdx.x / CG;
    const int row0 = blockIdx.x * BR + tr * 4;
    const int c0 = tc * 4;

    float4 acc[4];
    #pragma unroll
    for (int r = 0; r < 4; ++r) acc[r] = make_float4(0.f, 0.f, 0.f, 0.f);

    for (int k = 0; k < DIN; k += 4) {
        float4 w0 = *(const float4*)(W + (size_t)(k + 0) * DOUT + c0);
        float4 w1 = *(const float4*)(W + (size_t)(k + 1) * DOUT + c0);
        float4 w2 = *(const float4*)(W + (size_t)(k + 2) * DOUT + c0);
        float4 w3 = *(const float4*)(W + (size_t)(k + 3) * DOUT + c0);
        #pragma unroll
        for (int r = 0; r < 4; ++r) {
            int row = row0 + r;
            if (row < n) {
                float4 xv = *(const float4*)(X + (size_t)row * DIN + k);
                acc[r].x += xv.x * w0.x + xv.y * w1.x + xv.z * w2.x + xv.w * w3.x;
                acc[r].y += xv.x * w0.y + xv.y * w1.y + xv.z * w2.y + xv.w * w3.y;
                acc[r].z += xv.x * w0.z + xv.y * w1.z + xv.z * w2.z + xv.w * w3.z;
                acc[r].w += xv.x * w0.w + xv.y * w1.w + xv.z * w2.w + xv.w * w3.w;
            }
        }
    }
    #pragma unroll
    for (int r = 0; r < 4; ++r) {
        int row = row0 + r;
        if (row < n) *(float4*)(Y + (size_t)row * DOUT + c0) = acc[r];
    }
}

// ---- pull aggregation: out[v] = sum_e w_e * V[src_e]  + (a0+a1)*bias ----
// one wave per node; 4-edge batches for memory-level parallelism
template<int D>
__global__ void agg_kernel(const float* __restrict__ V, const int* __restrict__ offs,
                           const int* __restrict__ csr_src, const float* __restrict__ csr_w,
                           const float* __restrict__ bias, const float* __restrict__ attn,
                           float* __restrict__ out, int n) {
    constexpr int C = D / 64;
    int wid = (int)(((size_t)blockIdx.x * blockDim.x + threadIdx.x) >> 6);
    int lane = threadIdx.x & 63;
    if (wid >= n) return;
    int e0 = offs[wid], e1 = offs[wid + 1];

    float acc[C];
    #pragma unroll
    for (int c = 0; c < C; ++c) acc[c] = 0.f;

    int e = e0;
    for (; e + 4 <= e1; e += 4) {
        int s0 = csr_src[e + 0], s1 = csr_src[e + 1], s2 = csr_src[e + 2], s3 = csr_src[e + 3];
        float w0 = csr_w[e + 0], w1 = csr_w[e + 1], w2 = csr_w[e + 2], w3 = csr_w[e + 3];
        const float* p0 = V + (size_t)s0 * D + lane;
        const float* p1 = V + (size_t)s1 * D + lane;
        const float* p2 = V + (size_t)s2 * D + lane;
        const float* p3 = V + (size_t)s3 * D + lane;
        #pragma unroll
        for (int c = 0; c < C; ++c) {
            float g0 = p0[c * 64], g1 = p1[c * 64], g2 = p2[c * 64], g3 = p3[c * 64];
            acc[c] += w0 * g0;
            acc[c] += w1 * g1;
            acc[c] += w2 * g2;
            acc[c] += w3 * g3;
        }
    }
    for (; e < e1; ++e) {
        int s = csr_src[e];
        float w = csr_w[e];
        const float* p = V + (size_t)s * D + lane;
        #pragma unroll
        for (int c = 0; c < C; ++c) acc[c] += w * p[c * 64];
    }

    float bs = attn[0] + attn[1];
    #pragma unroll
    for (int c = 0; c < C; ++c)
        out[(size_t)wid * D + lane + c * 64] = acc[c] + bs * bias[lane + c * 64];
}

extern "C" void kernel_launch(void* const* d_in, const int* in_sizes, int n_in,
                              void* d_out, int out_size, void* d_ws, size_t ws_size,
                              hipStream_t stream) {
    const float* feat = (const float*)d_in[0];
    const int* src1   = (const int*)d_in[1];
    const int* dst1   = (const int*)d_in[2];
    const int* src2   = (const int*)d_in[3];
    const int* dst2   = (const int*)d_in[4];
    const float* attn = (const float*)d_in[5];
    const float* W1   = (const float*)d_in[6];
    const float* b1   = (const float*)d_in[7];
    const float* W2   = (const float*)d_in[8];
    const float* b2   = (const float*)d_in[9];
    float* out = (float*)d_out;

    const int N  = in_sizes[0] / DINF;   // 50000
    const int NE = in_sizes[1];          // 600000

    // workspace layout:
    // A[N*128] f | B[N*128] f | csr_src[2*NE] i | csr_w[2*NE] f |
    // offs[N+1] i | cursor[N] i | deg[4*N] i | rs[4*N] f
    float* ws = (float*)d_ws;
    float* A  = ws;
    float* B  = A + (size_t)N * DHID;
    int*   csr_src = (int*)(B + (size_t)N * DHID);
    float* csr_w   = (float*)(csr_src + 2 * (size_t)NE);
    int*   offs    = (int*)(csr_w + 2 * (size_t)NE);
    int*   cursor  = offs + (N + 1);
    int*   deg     = cursor + N;
    int*   d1o = deg;
    int*   d1i = deg + N;
    int*   d2o = deg + 2 * (size_t)N;
    int*   d2i = deg + 3 * (size_t)N;
    float* rs  = (float*)(deg + 4 * (size_t)N);
    float* rs1o = rs;
    float* rs1i = rs + N;
    float* rs2o = rs + 2 * (size_t)N;
    float* rs2i = rs + 3 * (size_t)N;

    hipMemsetAsync(deg, 0, sizeof(int) * 4 * (size_t)N, stream);

    int eb = (NE + 255) / 256;
    deg_count_kernel<<<eb, 256, 0, stream>>>(src1, d1o, NE);
    deg_count_kernel<<<eb, 256, 0, stream>>>(dst1, d1i, NE);
    deg_count_kernel<<<eb, 256, 0, stream>>>(src2, d2o, NE);
    deg_count_kernel<<<eb, 256, 0, stream>>>(dst2, d2i, NE);
    rsqrt_kernel<<<(4 * N + 255) / 256, 256, 0, stream>>>(deg, rs, 4 * N);

    // combined CSR over both graphs (layer-independent edge weights)
    scan_kernel<<<1, 256, 0, stream>>>(d1i, d2i, offs, cursor, N);
    fill_kernel<<<eb, 256, 0, stream>>>(src1, dst1, rs1o, rs1i, attn, 0, cursor, csr_src, csr_w, NE);
    fill_kernel<<<eb, 256, 0, stream>>>(src2, dst2, rs2o, rs2i, attn, 1, cursor, csr_src, csr_w, NE);

    // layer 1: A = feat @ W1 ; B = agg(A) + (a0+a1)*b1
    gemm_kernel<DINF, DHID><<<(N + 31) / 32, 256, 0, stream>>>(feat, W1, A, N);
    agg_kernel<DHID><<<(N + 3) / 4, 256, 0, stream>>>(A, offs, csr_src, csr_w, b1, attn, B, N);

    // layer 2: A = B @ W2 ; out = agg(A) + (a0+a1)*b2
    gemm_kernel<DHID, DOUTF><<<(N + 63) / 64, 256, 0, stream>>>(B, W2, A, N);
    agg_kernel<DOUTF><<<(N + 3) / 4, 256, 0, stream>>>(A, offs, csr_src, csr_w, b2, attn, out, N);
}

// Round 3
// 422.623 us; speedup vs baseline: 2.4352x; 1.4531x over previous
//
#include <hip/hip_runtime.h>

#define DINF 128
#define DHID 128
#define DOUTF 64

// ---- fused degree histogram for all 4 index arrays (blockIdx.y selects) ----
__global__ void deg4_kernel(const int* __restrict__ s1, const int* __restrict__ d1,
                            const int* __restrict__ s2, const int* __restrict__ d2,
                            int* __restrict__ deg, int N, int ne) {
    int i = blockIdx.x * 256 + threadIdx.x;
    if (i >= ne) return;
    const int* p = blockIdx.y == 0 ? s1 : blockIdx.y == 1 ? d1 : blockIdx.y == 2 ? s2 : d2;
    atomicAdd(&deg[(size_t)blockIdx.y * N + p[i]], 1);
}

// ---- scan phase 1: per-block (1024 elems) local exclusive scan + block sum ----
__global__ void scan1_kernel(const int* __restrict__ d1i, const int* __restrict__ d2i,
                             int* __restrict__ offs, int* __restrict__ bsum, int n) {
    __shared__ int warp_sums[4];
    int t = threadIdx.x;
    int lane = t & 63;
    int wid = t >> 6;
    int base = blockIdx.x * 1024 + t * 4;

    int v[4];
    int tot = 0;
    #pragma unroll
    for (int j = 0; j < 4; ++j) {
        int i = base + j;
        int d = (i < n) ? d1i[i] + d2i[i] : 0;
        v[j] = d; tot += d;
    }
    // inclusive scan of per-thread totals within wave
    int x = tot;
    #pragma unroll
    for (int off = 1; off < 64; off <<= 1) {
        int y = __shfl_up(x, off, 64);
        if (lane >= off) x += y;
    }
    if (lane == 63) warp_sums[wid] = x;
    __syncthreads();
    int wbase = 0;
    for (int w = 0; w < wid; ++w) wbase += warp_sums[w];
    int run = wbase + x - tot;   // exclusive prefix for this thread
    #pragma unroll
    for (int j = 0; j < 4; ++j) {
        int i = base + j;
        if (i < n) offs[i] = run;
        run += v[j];
    }
    if (t == 255) bsum[blockIdx.x] = run;   // block total
}

// ---- scan phase 2: single wave scans block sums (nb <= a few hundred) ----
__global__ void scan2_kernel(int* __restrict__ bsum, int* __restrict__ offs, int nb, int n) {
    int lane = threadIdx.x;
    int run = 0;
    for (int base = 0; base < nb; base += 64) {
        int i = base + lane;
        int v = (i < nb) ? bsum[i] : 0;
        int x = v;
        #pragma unroll
        for (int off = 1; off < 64; off <<= 1) {
            int y = __shfl_up(x, off, 64);
            if (lane >= off) x += y;
        }
        if (i < nb) bsum[i] = run + x - v;   // exclusive across all blocks
        run += __shfl(x, 63, 64);
    }
    if (lane == 0) offs[n] = run;            // grand total
}

// ---- scan phase 3: add block prefix, mirror into cursor ----
__global__ void scan3_kernel(int* __restrict__ offs, int* __restrict__ cursor,
                             const int* __restrict__ bsum, int n) {
    int base = blockIdx.x * 1024 + threadIdx.x * 4;
    int add = bsum[blockIdx.x];
    #pragma unroll
    for (int j = 0; j < 4; ++j) {
        int i = base + j;
        if (i < n) { int o = offs[i] + add; offs[i] = o; cursor[i] = o; }
    }
}

// ---- CSR fill: per edge, place src index + folded weight into dst bucket ----
__global__ void fill_kernel(const int* __restrict__ src, const int* __restrict__ dst,
                            const int* __restrict__ deg_out, const int* __restrict__ deg_in,
                            const float* __restrict__ attn, int ai,
                            int* __restrict__ cursor, int* __restrict__ csr_src,
                            float* __restrict__ csr_w, int ne) {
    int i = blockIdx.x * 256 + threadIdx.x;
    if (i >= ne) return;
    int s = src[i];
    int d = dst[i];
    int pos = atomicAdd(&cursor[d], 1);
    float w = attn[ai] * rsqrtf(fmaxf((float)deg_in[d], 1.0f))
                       * rsqrtf(fmaxf((float)deg_out[s], 1.0f));
    csr_src[pos] = s;
    csr_w[pos] = w;
}

// ---- dense GEMM  Y[n,DOUT] = X[n,DIN] @ W[DIN,DOUT]  (f32 vector ALU) ----
template<int DIN, int DOUT>
__global__ void gemm_kernel(const float* __restrict__ X, const float* __restrict__ W,
                            float* __restrict__ Y, int n) {
    constexpr int CG = DOUT / 4;
    constexpr int RG = 256 / CG;
    constexpr int BR = RG * 4;
    const int tc = threadIdx.x % CG;
    const int tr = threadIdx.x / CG;
    const int row0 = blockIdx.x * BR + tr * 4;
    const int c0 = tc * 4;

    float4 acc[4];
    #pragma unroll
    for (int r = 0; r < 4; ++r) acc[r] = make_float4(0.f, 0.f, 0.f, 0.f);

    for (int k = 0; k < DIN; k += 4) {
        float4 w0 = *(const float4*)(W + (size_t)(k + 0) * DOUT + c0);
        float4 w1 = *(const float4*)(W + (size_t)(k + 1) * DOUT + c0);
        float4 w2 = *(const float4*)(W + (size_t)(k + 2) * DOUT + c0);
        float4 w3 = *(const float4*)(W + (size_t)(k + 3) * DOUT + c0);
        #pragma unroll
        for (int r = 0; r < 4; ++r) {
            int row = row0 + r;
            if (row < n) {
                float4 xv = *(const float4*)(X + (size_t)row * DIN + k);
                acc[r].x += xv.x * w0.x + xv.y * w1.x + xv.z * w2.x + xv.w * w3.x;
                acc[r].y += xv.x * w0.y + xv.y * w1.y + xv.z * w2.y + xv.w * w3.y;
                acc[r].z += xv.x * w0.z + xv.y * w1.z + xv.z * w2.z + xv.w * w3.z;
                acc[r].w += xv.x * w0.w + xv.y * w1.w + xv.z * w2.w + xv.w * w3.w;
            }
        }
    }
    #pragma unroll
    for (int r = 0; r < 4; ++r) {
        int row = row0 + r;
        if (row < n) *(float4*)(Y + (size_t)row * DOUT + c0) = acc[r];
    }
}

// ---- pull aggregation: out[v] = sum_e w_e * V[src_e]  + (a0+a1)*bias ----
template<int D>
__global__ void agg_kernel(const float* __restrict__ V, const int* __restrict__ offs,
                           const int* __restrict__ csr_src, const float* __restrict__ csr_w,
                           const float* __restrict__ bias, const float* __restrict__ attn,
                           float* __restrict__ out, int n) {
    constexpr int C = D / 64;
    int wid = (int)(((size_t)blockIdx.x * blockDim.x + threadIdx.x) >> 6);
    int lane = threadIdx.x & 63;
    if (wid >= n) return;
    int e0 = offs[wid], e1 = offs[wid + 1];

    float acc[C];
    #pragma unroll
    for (int c = 0; c < C; ++c) acc[c] = 0.f;

    int e = e0;
    for (; e + 4 <= e1; e += 4) {
        int s0 = csr_src[e + 0], s1 = csr_src[e + 1], s2 = csr_src[e + 2], s3 = csr_src[e + 3];
        float w0 = csr_w[e + 0], w1 = csr_w[e + 1], w2 = csr_w[e + 2], w3 = csr_w[e + 3];
        const float* p0 = V + (size_t)s0 * D + lane;
        const float* p1 = V + (size_t)s1 * D + lane;
        const float* p2 = V + (size_t)s2 * D + lane;
        const float* p3 = V + (size_t)s3 * D + lane;
        #pragma unroll
        for (int c = 0; c < C; ++c) {
            float g0 = p0[c * 64], g1 = p1[c * 64], g2 = p2[c * 64], g3 = p3[c * 64];
            acc[c] += w0 * g0;
            acc[c] += w1 * g1;
            acc[c] += w2 * g2;
            acc[c] += w3 * g3;
        }
    }
    for (; e < e1; ++e) {
        int s = csr_src[e];
        float w = csr_w[e];
        const float* p = V + (size_t)s * D + lane;
        #pragma unroll
        for (int c = 0; c < C; ++c) acc[c] += w * p[c * 64];
    }

    float bs = attn[0] + attn[1];
    #pragma unroll
    for (int c = 0; c < C; ++c)
        out[(size_t)wid * D + lane + c * 64] = acc[c] + bs * bias[lane + c * 64];
}

extern "C" void kernel_launch(void* const* d_in, const int* in_sizes, int n_in,
                              void* d_out, int out_size, void* d_ws, size_t ws_size,
                              hipStream_t stream) {
    const float* feat = (const float*)d_in[0];
    const int* src1   = (const int*)d_in[1];
    const int* dst1   = (const int*)d_in[2];
    const int* src2   = (const int*)d_in[3];
    const int* dst2   = (const int*)d_in[4];
    const float* attn = (const float*)d_in[5];
    const float* W1   = (const float*)d_in[6];
    const float* b1   = (const float*)d_in[7];
    const float* W2   = (const float*)d_in[8];
    const float* b2   = (const float*)d_in[9];
    float* out = (float*)d_out;

    const int N  = in_sizes[0] / DINF;   // 50000
    const int NE = in_sizes[1];          // 600000
    const int NB = (N + 1023) / 1024;    // scan blocks

    // workspace layout:
    // A[N*128] f | B[N*128] f | csr_src[2*NE] i | csr_w[2*NE] f |
    // offs[N+1] i | cursor[N] i | deg[4*N] i | bsum[NB] i
    float* ws = (float*)d_ws;
    float* A  = ws;
    float* B  = A + (size_t)N * DHID;
    int*   csr_src = (int*)(B + (size_t)N * DHID);
    float* csr_w   = (float*)(csr_src + 2 * (size_t)NE);
    int*   offs    = (int*)(csr_w + 2 * (size_t)NE);
    int*   cursor  = offs + (N + 1);
    int*   deg     = cursor + N;
    int*   d1o = deg;
    int*   d1i = deg + N;
    int*   d2o = deg + 2 * (size_t)N;
    int*   d2i = deg + 3 * (size_t)N;
    int*   bsum = deg + 4 * (size_t)N;

    hipMemsetAsync(deg, 0, sizeof(int) * 4 * (size_t)N, stream);

    int eb = (NE + 255) / 256;
    deg4_kernel<<<dim3(eb, 4), 256, 0, stream>>>(src1, dst1, src2, dst2, deg, N, NE);

    // hierarchical exclusive scan of combined in-degree -> offs, cursor
    scan1_kernel<<<NB, 256, 0, stream>>>(d1i, d2i, offs, bsum, N);
    scan2_kernel<<<1, 64, 0, stream>>>(bsum, offs, NB, N);
    scan3_kernel<<<NB, 256, 0, stream>>>(offs, cursor, bsum, N);

    // combined CSR over both graphs (layer-independent edge weights)
    fill_kernel<<<eb, 256, 0, stream>>>(src1, dst1, d1o, d1i, attn, 0, cursor, csr_src, csr_w, NE);
    fill_kernel<<<eb, 256, 0, stream>>>(src2, dst2, d2o, d2i, attn, 1, cursor, csr_src, csr_w, NE);

    // layer 1: A = feat @ W1 ; B = agg(A) + (a0+a1)*b1
    gemm_kernel<DINF, DHID><<<(N + 31) / 32, 256, 0, stream>>>(feat, W1, A, N);
    agg_kernel<DHID><<<(N + 3) / 4, 256, 0, stream>>>(A, offs, csr_src, csr_w, b1, attn, B, N);

    // layer 2: A = B @ W2 ; out = agg(A) + (a0+a1)*b2
    gemm_kernel<DHID, DOUTF><<<(N + 63) / 64, 256, 0, stream>>>(B, W2, A, N);
    agg_kernel<DOUTF><<<(N + 3) / 4, 256, 0, stream>>>(A, offs, csr_src, csr_w, b2, attn, out, N);
}

// Round 4
// 335.150 us; speedup vs baseline: 3.0708x; 1.2610x over previous
//
#include <hip/hip_runtime.h>

#define DINF 128
#define DHID 128
#define DOUTF 64

#define CHUNK 12544   // histogram slots per LDS chunk (49 KB)
#define NCHUNK 4      // ceil(50000 / 12544)
#define ECH 16        // edge slices

// ---- LDS-privatized degree histogram for all 4 index arrays ----
// grid (ECH, NCHUNK, 4), block 1024, dyn LDS = CHUNK*4 bytes
__global__ void deg_priv_kernel(const int* __restrict__ s1, const int* __restrict__ d1,
                                const int* __restrict__ s2, const int* __restrict__ d2,
                                int* __restrict__ deg, int N, int ne) {
    extern __shared__ int h[];
    int t = threadIdx.x;
    #pragma unroll
    for (int j = t; j < CHUNK; j += 1024) h[j] = 0;
    __syncthreads();

    const int* p = blockIdx.z == 0 ? s1 : blockIdx.z == 1 ? d1 : blockIdx.z == 2 ? s2 : d2;
    int lo = blockIdx.y * CHUNK;
    int per = (ne + ECH - 1) / ECH;
    int e0 = blockIdx.x * per;
    int e1 = e0 + per < ne ? e0 + per : ne;
    for (int i = e0 + t; i < e1; i += 1024) {
        int idx = p[i] - lo;
        if ((unsigned)idx < (unsigned)CHUNK) atomicAdd(&h[idx], 1);
    }
    __syncthreads();

    int* dz = deg + (size_t)blockIdx.z * N;
    for (int j = t; j < CHUNK; j += 1024) {
        int node = lo + j;
        int v = h[j];
        if (v && node < N) atomicAdd(&dz[node], v);
    }
}

// ---- scan phase 1: per-block (1024 elems) local exclusive scan + block sum ----
__global__ void scan1_kernel(const int* __restrict__ d1i, const int* __restrict__ d2i,
                             int* __restrict__ offs, int* __restrict__ bsum, int n) {
    __shared__ int warp_sums[4];
    int t = threadIdx.x;
    int lane = t & 63;
    int wid = t >> 6;
    int base = blockIdx.x * 1024 + t * 4;

    int v[4];
    int tot = 0;
    #pragma unroll
    for (int j = 0; j < 4; ++j) {
        int i = base + j;
        int d = (i < n) ? d1i[i] + d2i[i] : 0;
        v[j] = d; tot += d;
    }
    int x = tot;
    #pragma unroll
    for (int off = 1; off < 64; off <<= 1) {
        int y = __shfl_up(x, off, 64);
        if (lane >= off) x += y;
    }
    if (lane == 63) warp_sums[wid] = x;
    __syncthreads();
    int wbase = 0;
    for (int w = 0; w < wid; ++w) wbase += warp_sums[w];
    int run = wbase + x - tot;
    #pragma unroll
    for (int j = 0; j < 4; ++j) {
        int i = base + j;
        if (i < n) offs[i] = run;
        run += v[j];
    }
    if (t == 255) bsum[blockIdx.x] = run;
}

// ---- scan phase 2: single wave scans block sums ----
__global__ void scan2_kernel(int* __restrict__ bsum, int* __restrict__ offs, int nb, int n) {
    int lane = threadIdx.x;
    int run = 0;
    for (int base = 0; base < nb; base += 64) {
        int i = base + lane;
        int v = (i < nb) ? bsum[i] : 0;
        int x = v;
        #pragma unroll
        for (int off = 1; off < 64; off <<= 1) {
            int y = __shfl_up(x, off, 64);
            if (lane >= off) x += y;
        }
        if (i < nb) bsum[i] = run + x - v;
        run += __shfl(x, 63, 64);
    }
    if (lane == 0) offs[n] = run;
}

// ---- scan phase 3: add block prefix, mirror into cursor ----
__global__ void scan3_kernel(int* __restrict__ offs, int* __restrict__ cursor,
                             const int* __restrict__ bsum, int n) {
    int base = blockIdx.x * 1024 + threadIdx.x * 4;
    int add = bsum[blockIdx.x];
    #pragma unroll
    for (int j = 0; j < 4; ++j) {
        int i = base + j;
        if (i < n) { int o = offs[i] + add; offs[i] = o; cursor[i] = o; }
    }
}

// ---- CSR fill: packed int2{src, weight_bits} per edge ----
__global__ void fill_kernel(const int* __restrict__ src, const int* __restrict__ dst,
                            const int* __restrict__ deg_out, const int* __restrict__ deg_in,
                            const float* __restrict__ attn, int ai,
                            int* __restrict__ cursor, int2* __restrict__ csr, int ne) {
    int i = blockIdx.x * 256 + threadIdx.x;
    if (i >= ne) return;
    int s = src[i];
    int d = dst[i];
    int pos = atomicAdd(&cursor[d], 1);
    float w = attn[ai] * rsqrtf(fmaxf((float)deg_in[d], 1.0f))
                       * rsqrtf(fmaxf((float)deg_out[s], 1.0f));
    csr[pos] = make_int2(s, __float_as_int(w));
}

// ---- dense GEMM  Y[n,DOUT] = X[n,DIN] @ W[DIN,DOUT]  (f32 vector ALU) ----
template<int DIN, int DOUT>
__global__ void gemm_kernel(const float* __restrict__ X, const float* __restrict__ W,
                            float* __restrict__ Y, int n) {
    constexpr int CG = DOUT / 4;
    constexpr int RG = 256 / CG;
    constexpr int BR = RG * 4;
    const int tc = threadIdx.x % CG;
    const int tr = threadIdx.x / CG;
    const int row0 = blockIdx.x * BR + tr * 4;
    const int c0 = tc * 4;

    float4 acc[4];
    #pragma unroll
    for (int r = 0; r < 4; ++r) acc[r] = make_float4(0.f, 0.f, 0.f, 0.f);

    for (int k = 0; k < DIN; k += 4) {
        float4 w0 = *(const float4*)(W + (size_t)(k + 0) * DOUT + c0);
        float4 w1 = *(const float4*)(W + (size_t)(k + 1) * DOUT + c0);
        float4 w2 = *(const float4*)(W + (size_t)(k + 2) * DOUT + c0);
        float4 w3 = *(const float4*)(W + (size_t)(k + 3) * DOUT + c0);
        #pragma unroll
        for (int r = 0; r < 4; ++r) {
            int row = row0 + r;
            if (row < n) {
                float4 xv = *(const float4*)(X + (size_t)row * DIN + k);
                acc[r].x += xv.x * w0.x + xv.y * w1.x + xv.z * w2.x + xv.w * w3.x;
                acc[r].y += xv.x * w0.y + xv.y * w1.y + xv.z * w2.y + xv.w * w3.y;
                acc[r].z += xv.x * w0.z + xv.y * w1.z + xv.z * w2.z + xv.w * w3.z;
                acc[r].w += xv.x * w0.w + xv.y * w1.w + xv.z * w2.w + xv.w * w3.w;
            }
        }
    }
    #pragma unroll
    for (int r = 0; r < 4; ++r) {
        int row = row0 + r;
        if (row < n) *(float4*)(Y + (size_t)row * DOUT + c0) = acc[r];
    }
}

// ---- pull aggregation: out[v] = sum_e w_e * V[src_e]  + (a0+a1)*bias ----
template<int D>
__global__ void agg_kernel(const float* __restrict__ V, const int* __restrict__ offs,
                           const int2* __restrict__ csr,
                           const float* __restrict__ bias, const float* __restrict__ attn,
                           float* __restrict__ out, int n) {
    constexpr int C = D / 64;
    int wid = (int)(((size_t)blockIdx.x * blockDim.x + threadIdx.x) >> 6);
    int lane = threadIdx.x & 63;
    if (wid >= n) return;
    int e0 = offs[wid], e1 = offs[wid + 1];

    float acc[C];
    #pragma unroll
    for (int c = 0; c < C; ++c) acc[c] = 0.f;

    int e = e0;
    for (; e + 4 <= e1; e += 4) {
        int2 c0v = csr[e + 0], c1v = csr[e + 1], c2v = csr[e + 2], c3v = csr[e + 3];
        float w0 = __int_as_float(c0v.y), w1 = __int_as_float(c1v.y);
        float w2 = __int_as_float(c2v.y), w3 = __int_as_float(c3v.y);
        const float* p0 = V + (size_t)c0v.x * D + lane;
        const float* p1 = V + (size_t)c1v.x * D + lane;
        const float* p2 = V + (size_t)c2v.x * D + lane;
        const float* p3 = V + (size_t)c3v.x * D + lane;
        #pragma unroll
        for (int c = 0; c < C; ++c) {
            float g0 = p0[c * 64], g1 = p1[c * 64], g2 = p2[c * 64], g3 = p3[c * 64];
            acc[c] += w0 * g0;
            acc[c] += w1 * g1;
            acc[c] += w2 * g2;
            acc[c] += w3 * g3;
        }
    }
    for (; e < e1; ++e) {
        int2 cv = csr[e];
        float w = __int_as_float(cv.y);
        const float* p = V + (size_t)cv.x * D + lane;
        #pragma unroll
        for (int c = 0; c < C; ++c) acc[c] += w * p[c * 64];
    }

    float bs = attn[0] + attn[1];
    #pragma unroll
    for (int c = 0; c < C; ++c)
        out[(size_t)wid * D + lane + c * 64] = acc[c] + bs * bias[lane + c * 64];
}

extern "C" void kernel_launch(void* const* d_in, const int* in_sizes, int n_in,
                              void* d_out, int out_size, void* d_ws, size_t ws_size,
                              hipStream_t stream) {
    const float* feat = (const float*)d_in[0];
    const int* src1   = (const int*)d_in[1];
    const int* dst1   = (const int*)d_in[2];
    const int* src2   = (const int*)d_in[3];
    const int* dst2   = (const int*)d_in[4];
    const float* attn = (const float*)d_in[5];
    const float* W1   = (const float*)d_in[6];
    const float* b1   = (const float*)d_in[7];
    const float* W2   = (const float*)d_in[8];
    const float* b2   = (const float*)d_in[9];
    float* out = (float*)d_out;

    const int N  = in_sizes[0] / DINF;   // 50000
    const int NE = in_sizes[1];          // 600000
    const int NB = (N + 1023) / 1024;    // scan blocks

    // workspace layout:
    // A[N*128] f | B[N*128] f | csr[2*NE] int2 | offs[N+1] i | cursor[N] i |
    // deg[4*N] i | bsum[NB] i
    float* ws = (float*)d_ws;
    float* A  = ws;
    float* B  = A + (size_t)N * DHID;
    int2*  csr = (int2*)(B + (size_t)N * DHID);
    int*   offs = (int*)(csr + 2 * (size_t)NE);
    int*   cursor = offs + (N + 1);
    int*   deg = cursor + N;
    int*   d1o = deg;
    int*   d1i = deg + N;
    int*   d2o = deg + 2 * (size_t)N;
    int*   d2i = deg + 3 * (size_t)N;
    int*   bsum = deg + 4 * (size_t)N;

    hipMemsetAsync(deg, 0, sizeof(int) * 4 * (size_t)N, stream);

    deg_priv_kernel<<<dim3(ECH, NCHUNK, 4), 1024, CHUNK * sizeof(int), stream>>>(
        src1, dst1, src2, dst2, deg, N, NE);

    // hierarchical exclusive scan of combined in-degree -> offs, cursor
    scan1_kernel<<<NB, 256, 0, stream>>>(d1i, d2i, offs, bsum, N);
    scan2_kernel<<<1, 64, 0, stream>>>(bsum, offs, NB, N);
    scan3_kernel<<<NB, 256, 0, stream>>>(offs, cursor, bsum, N);

    // combined CSR over both graphs (layer-independent edge weights)
    int eb = (NE + 255) / 256;
    fill_kernel<<<eb, 256, 0, stream>>>(src1, dst1, d1o, d1i, attn, 0, cursor, csr, NE);
    fill_kernel<<<eb, 256, 0, stream>>>(src2, dst2, d2o, d2i, attn, 1, cursor, csr, NE);

    // layer 1: A = feat @ W1 ; B = agg(A) + (a0+a1)*b1
    gemm_kernel<DINF, DHID><<<(N + 31) / 32, 256, 0, stream>>>(feat, W1, A, N);
    agg_kernel<DHID><<<(N + 3) / 4, 256, 0, stream>>>(A, offs, csr, b1, attn, B, N);

    // layer 2: A = B @ W2 ; out = agg(A) + (a0+a1)*b2
    gemm_kernel<DHID, DOUTF><<<(N + 63) / 64, 256, 0, stream>>>(B, W2, A, N);
    agg_kernel<DOUTF><<<(N + 3) / 4, 256, 0, stream>>>(A, offs, csr, b2, attn, out, N);
}

// Round 5
// 291.735 us; speedup vs baseline: 3.5277x; 1.1488x over previous
//
#include <hip/hip_runtime.h>

#define DINF 128
#define DHID 128
#define DOUTF 64

#define CHUNK 12544   // histogram slots per LDS chunk (49 KB)
#define NCHUNK 4      // ceil(50000 / 12544)
#define ECH 16        // edge slices

typedef unsigned short ushort_t;
typedef unsigned int uint_t;

__device__ __forceinline__ ushort_t f2b(float x) {   // f32 -> bf16 RNE
    uint_t u = __float_as_uint(x);
    u += 0x7fffu + ((u >> 16) & 1u);
    return (ushort_t)(u >> 16);
}
__device__ __forceinline__ float b2f_lo(uint_t u) { return __uint_as_float(u << 16); }
__device__ __forceinline__ float b2f_hi(uint_t u) { return __uint_as_float(u & 0xffff0000u); }

// ---- LDS-privatized degree histogram for all 4 index arrays ----
__global__ void deg_priv_kernel(const int* __restrict__ s1, const int* __restrict__ d1,
                                const int* __restrict__ s2, const int* __restrict__ d2,
                                int* __restrict__ deg, int N, int ne) {
    extern __shared__ int h[];
    int t = threadIdx.x;
    for (int j = t; j < CHUNK; j += 1024) h[j] = 0;
    __syncthreads();

    const int* p = blockIdx.z == 0 ? s1 : blockIdx.z == 1 ? d1 : blockIdx.z == 2 ? s2 : d2;
    int lo = blockIdx.y * CHUNK;
    int per = (ne + ECH - 1) / ECH;
    int e0 = blockIdx.x * per;
    int e1 = e0 + per < ne ? e0 + per : ne;
    for (int i = e0 + t; i < e1; i += 1024) {
        int idx = p[i] - lo;
        if ((unsigned)idx < (unsigned)CHUNK) atomicAdd(&h[idx], 1);
    }
    __syncthreads();

    int* dz = deg + (size_t)blockIdx.z * N;
    for (int j = t; j < CHUNK; j += 1024) {
        int node = lo + j;
        int v = h[j];
        if (v && node < N) atomicAdd(&dz[node], v);
    }
}

// ---- scan phase 1 ----
__global__ void scan1_kernel(const int* __restrict__ d1i, const int* __restrict__ d2i,
                             int* __restrict__ offs, int* __restrict__ bsum, int n) {
    __shared__ int warp_sums[4];
    int t = threadIdx.x;
    int lane = t & 63;
    int wid = t >> 6;
    int base = blockIdx.x * 1024 + t * 4;

    int v[4];
    int tot = 0;
    #pragma unroll
    for (int j = 0; j < 4; ++j) {
        int i = base + j;
        int d = (i < n) ? d1i[i] + d2i[i] : 0;
        v[j] = d; tot += d;
    }
    int x = tot;
    #pragma unroll
    for (int off = 1; off < 64; off <<= 1) {
        int y = __shfl_up(x, off, 64);
        if (lane >= off) x += y;
    }
    if (lane == 63) warp_sums[wid] = x;
    __syncthreads();
    int wbase = 0;
    for (int w = 0; w < wid; ++w) wbase += warp_sums[w];
    int run = wbase + x - tot;
    #pragma unroll
    for (int j = 0; j < 4; ++j) {
        int i = base + j;
        if (i < n) offs[i] = run;
        run += v[j];
    }
    if (t == 255) bsum[blockIdx.x] = run;
}

// ---- scan phase 2 ----
__global__ void scan2_kernel(int* __restrict__ bsum, int* __restrict__ offs, int nb, int n) {
    int lane = threadIdx.x;
    int run = 0;
    for (int base = 0; base < nb; base += 64) {
        int i = base + lane;
        int v = (i < nb) ? bsum[i] : 0;
        int x = v;
        #pragma unroll
        for (int off = 1; off < 64; off <<= 1) {
            int y = __shfl_up(x, off, 64);
            if (lane >= off) x += y;
        }
        if (i < nb) bsum[i] = run + x - v;
        run += __shfl(x, 63, 64);
    }
    if (lane == 0) offs[n] = run;
}

// ---- scan phase 3 ----
__global__ void scan3_kernel(int* __restrict__ offs, int* __restrict__ cursor,
                             const int* __restrict__ bsum, int n) {
    int base = blockIdx.x * 1024 + threadIdx.x * 4;
    int add = bsum[blockIdx.x];
    #pragma unroll
    for (int j = 0; j < 4; ++j) {
        int i = base + j;
        if (i < n) { int o = offs[i] + add; offs[i] = o; cursor[i] = o; }
    }
}

// ---- CSR fill ----
__global__ void fill_kernel(const int* __restrict__ src, const int* __restrict__ dst,
                            const int* __restrict__ deg_out, const int* __restrict__ deg_in,
                            const float* __restrict__ attn, int ai,
                            int* __restrict__ cursor, int2* __restrict__ csr, int ne) {
    int i = blockIdx.x * 256 + threadIdx.x;
    if (i >= ne) return;
    int s = src[i];
    int d = dst[i];
    int pos = atomicAdd(&cursor[d], 1);
    float w = attn[ai] * rsqrtf(fmaxf((float)deg_in[d], 1.0f))
                       * rsqrtf(fmaxf((float)deg_out[s], 1.0f));
    csr[pos] = make_int2(s, __float_as_int(w));
}

// ---- GEMM f32-in, bf16-out ----
template<int DIN, int DOUT>
__global__ void gemm_f32in_kernel(const float* __restrict__ X, const float* __restrict__ W,
                                  ushort_t* __restrict__ Y, int n) {
    constexpr int CG = DOUT / 4;
    constexpr int RG = 256 / CG;
    constexpr int BR = RG * 4;
    const int tc = threadIdx.x % CG;
    const int tr = threadIdx.x / CG;
    const int row0 = blockIdx.x * BR + tr * 4;
    const int c0 = tc * 4;

    float4 acc[4];
    #pragma unroll
    for (int r = 0; r < 4; ++r) acc[r] = make_float4(0.f, 0.f, 0.f, 0.f);

    for (int k = 0; k < DIN; k += 4) {
        float4 w0 = *(const float4*)(W + (size_t)(k + 0) * DOUT + c0);
        float4 w1 = *(const float4*)(W + (size_t)(k + 1) * DOUT + c0);
        float4 w2 = *(const float4*)(W + (size_t)(k + 2) * DOUT + c0);
        float4 w3 = *(const float4*)(W + (size_t)(k + 3) * DOUT + c0);
        #pragma unroll
        for (int r = 0; r < 4; ++r) {
            int row = row0 + r;
            if (row < n) {
                float4 xv = *(const float4*)(X + (size_t)row * DIN + k);
                acc[r].x += xv.x * w0.x + xv.y * w1.x + xv.z * w2.x + xv.w * w3.x;
                acc[r].y += xv.x * w0.y + xv.y * w1.y + xv.z * w2.y + xv.w * w3.y;
                acc[r].z += xv.x * w0.z + xv.y * w1.z + xv.z * w2.z + xv.w * w3.z;
                acc[r].w += xv.x * w0.w + xv.y * w1.w + xv.z * w2.w + xv.w * w3.w;
            }
        }
    }
    #pragma unroll
    for (int r = 0; r < 4; ++r) {
        int row = row0 + r;
        if (row < n) {
            ushort4 o; o.x = f2b(acc[r].x); o.y = f2b(acc[r].y);
            o.z = f2b(acc[r].z); o.w = f2b(acc[r].w);
            *(ushort4*)(Y + (size_t)row * DOUT + c0) = o;
        }
    }
}

// ---- GEMM bf16-in, bf16-out ----
template<int DIN, int DOUT>
__global__ void gemm_b16in_kernel(const ushort_t* __restrict__ X, const float* __restrict__ W,
                                  ushort_t* __restrict__ Y, int n) {
    constexpr int CG = DOUT / 4;
    constexpr int RG = 256 / CG;
    constexpr int BR = RG * 4;
    const int tc = threadIdx.x % CG;
    const int tr = threadIdx.x / CG;
    const int row0 = blockIdx.x * BR + tr * 4;
    const int c0 = tc * 4;

    float4 acc[4];
    #pragma unroll
    for (int r = 0; r < 4; ++r) acc[r] = make_float4(0.f, 0.f, 0.f, 0.f);

    for (int k = 0; k < DIN; k += 4) {
        float4 w0 = *(const float4*)(W + (size_t)(k + 0) * DOUT + c0);
        float4 w1 = *(const float4*)(W + (size_t)(k + 1) * DOUT + c0);
        float4 w2 = *(const float4*)(W + (size_t)(k + 2) * DOUT + c0);
        float4 w3 = *(const float4*)(W + (size_t)(k + 3) * DOUT + c0);
        #pragma unroll
        for (int r = 0; r < 4; ++r) {
            int row = row0 + r;
            if (row < n) {
                uint2 xu = *(const uint2*)(X + (size_t)row * DIN + k);
                float x0 = b2f_lo(xu.x), x1 = b2f_hi(xu.x);
                float x2 = b2f_lo(xu.y), x3 = b2f_hi(xu.y);
                acc[r].x += x0 * w0.x + x1 * w1.x + x2 * w2.x + x3 * w3.x;
                acc[r].y += x0 * w0.y + x1 * w1.y + x2 * w2.y + x3 * w3.y;
                acc[r].z += x0 * w0.z + x1 * w1.z + x2 * w2.z + x3 * w3.z;
                acc[r].w += x0 * w0.w + x1 * w1.w + x2 * w2.w + x3 * w3.w;
            }
        }
    }
    #pragma unroll
    for (int r = 0; r < 4; ++r) {
        int row = row0 + r;
        if (row < n) {
            ushort4 o; o.x = f2b(acc[r].x); o.y = f2b(acc[r].y);
            o.z = f2b(acc[r].z); o.w = f2b(acc[r].w);
            *(ushort4*)(Y + (size_t)row * DOUT + c0) = o;
        }
    }
}

// ---- agg D=128: gather bf16 rows (uint = 2 bf16 per lane), write bf16 x1 ----
__global__ void agg128_kernel(const ushort_t* __restrict__ V, const int* __restrict__ offs,
                              const int2* __restrict__ csr, const float* __restrict__ bias,
                              const float* __restrict__ attn, uint_t* __restrict__ out, int n) {
    int wid = (int)(((size_t)blockIdx.x * blockDim.x + threadIdx.x) >> 6);
    int lane = threadIdx.x & 63;
    if (wid >= n) return;
    int e0 = offs[wid], e1 = offs[wid + 1];

    float acc0 = 0.f, acc1 = 0.f;

    int e = e0;
    for (; e + 4 <= e1; e += 4) {
        int2 c0v = csr[e + 0], c1v = csr[e + 1], c2v = csr[e + 2], c3v = csr[e + 3];
        float w0 = __int_as_float(c0v.y), w1 = __int_as_float(c1v.y);
        float w2 = __int_as_float(c2v.y), w3 = __int_as_float(c3v.y);
        uint_t u0 = ((const uint_t*)(V + (size_t)c0v.x * 128))[lane];
        uint_t u1 = ((const uint_t*)(V + (size_t)c1v.x * 128))[lane];
        uint_t u2 = ((const uint_t*)(V + (size_t)c2v.x * 128))[lane];
        uint_t u3 = ((const uint_t*)(V + (size_t)c3v.x * 128))[lane];
        acc0 += w0 * b2f_lo(u0); acc1 += w0 * b2f_hi(u0);
        acc0 += w1 * b2f_lo(u1); acc1 += w1 * b2f_hi(u1);
        acc0 += w2 * b2f_lo(u2); acc1 += w2 * b2f_hi(u2);
        acc0 += w3 * b2f_lo(u3); acc1 += w3 * b2f_hi(u3);
    }
    for (; e < e1; ++e) {
        int2 cv = csr[e];
        float w = __int_as_float(cv.y);
        uint_t u = ((const uint_t*)(V + (size_t)cv.x * 128))[lane];
        acc0 += w * b2f_lo(u); acc1 += w * b2f_hi(u);
    }

    float bs = attn[0] + attn[1];
    float2 bb = ((const float2*)bias)[lane];
    float o0 = acc0 + bs * bb.x;
    float o1 = acc1 + bs * bb.y;
    out[(size_t)wid * 64 + lane] = (uint_t)f2b(o0) | ((uint_t)f2b(o1) << 16);
}

// ---- agg D=64: gather bf16 rows (ushort per lane), write f32 output ----
__global__ void agg64_kernel(const ushort_t* __restrict__ V, const int* __restrict__ offs,
                             const int2* __restrict__ csr, const float* __restrict__ bias,
                             const float* __restrict__ attn, float* __restrict__ out, int n) {
    int wid = (int)(((size_t)blockIdx.x * blockDim.x + threadIdx.x) >> 6);
    int lane = threadIdx.x & 63;
    if (wid >= n) return;
    int e0 = offs[wid], e1 = offs[wid + 1];

    float acc = 0.f;

    int e = e0;
    for (; e + 4 <= e1; e += 4) {
        int2 c0v = csr[e + 0], c1v = csr[e + 1], c2v = csr[e + 2], c3v = csr[e + 3];
        float w0 = __int_as_float(c0v.y), w1 = __int_as_float(c1v.y);
        float w2 = __int_as_float(c2v.y), w3 = __int_as_float(c3v.y);
        float g0 = __uint_as_float(((uint_t)V[(size_t)c0v.x * 64 + lane]) << 16);
        float g1 = __uint_as_float(((uint_t)V[(size_t)c1v.x * 64 + lane]) << 16);
        float g2 = __uint_as_float(((uint_t)V[(size_t)c2v.x * 64 + lane]) << 16);
        float g3 = __uint_as_float(((uint_t)V[(size_t)c3v.x * 64 + lane]) << 16);
        acc += w0 * g0 + w1 * g1 + w2 * g2 + w3 * g3;
    }
    for (; e < e1; ++e) {
        int2 cv = csr[e];
        float w = __int_as_float(cv.y);
        float g = __uint_as_float(((uint_t)V[(size_t)cv.x * 64 + lane]) << 16);
        acc += w * g;
    }

    float bs = attn[0] + attn[1];
    out[(size_t)wid * 64 + lane] = acc + bs * bias[lane];
}

extern "C" void kernel_launch(void* const* d_in, const int* in_sizes, int n_in,
                              void* d_out, int out_size, void* d_ws, size_t ws_size,
                              hipStream_t stream) {
    const float* feat = (const float*)d_in[0];
    const int* src1   = (const int*)d_in[1];
    const int* dst1   = (const int*)d_in[2];
    const int* src2   = (const int*)d_in[3];
    const int* dst2   = (const int*)d_in[4];
    const float* attn = (const float*)d_in[5];
    const float* W1   = (const float*)d_in[6];
    const float* b1   = (const float*)d_in[7];
    const float* W2   = (const float*)d_in[8];
    const float* b2   = (const float*)d_in[9];
    float* out = (float*)d_out;

    const int N  = in_sizes[0] / DINF;   // 50000
    const int NE = in_sizes[1];          // 600000
    const int NB = (N + 1023) / 1024;    // scan blocks

    // workspace layout (16B-aligned chunks):
    // A bf16[N*128] | B bf16[N*128] | C bf16[N*64] | csr int2[2*NE] |
    // offs[N+1] | cursor[N] | deg[4*N] | bsum[NB]
    char* wsb = (char*)d_ws;
    ushort_t* A = (ushort_t*)wsb;                       // 12.8 MB
    ushort_t* B = A + (size_t)N * DHID;                 // 12.8 MB
    ushort_t* C = B + (size_t)N * DHID;                 // 6.4 MB
    int2* csr   = (int2*)(C + (size_t)N * DOUTF);       // 9.6 MB
    int* offs   = (int*)(csr + 2 * (size_t)NE);
    int* cursor = offs + (N + 1);
    int* deg    = cursor + N;
    int* d1o = deg;
    int* d1i = deg + N;
    int* d2o = deg + 2 * (size_t)N;
    int* d2i = deg + 3 * (size_t)N;
    int* bsum = deg + 4 * (size_t)N;

    hipMemsetAsync(deg, 0, sizeof(int) * 4 * (size_t)N, stream);

    deg_priv_kernel<<<dim3(ECH, NCHUNK, 4), 1024, CHUNK * sizeof(int), stream>>>(
        src1, dst1, src2, dst2, deg, N, NE);

    scan1_kernel<<<NB, 256, 0, stream>>>(d1i, d2i, offs, bsum, N);
    scan2_kernel<<<1, 64, 0, stream>>>(bsum, offs, NB, N);
    scan3_kernel<<<NB, 256, 0, stream>>>(offs, cursor, bsum, N);

    int eb = (NE + 255) / 256;
    fill_kernel<<<eb, 256, 0, stream>>>(src1, dst1, d1o, d1i, attn, 0, cursor, csr, NE);
    fill_kernel<<<eb, 256, 0, stream>>>(src2, dst2, d2o, d2i, attn, 1, cursor, csr, NE);

    // layer 1: A = bf16(feat @ W1) ; B = bf16(agg(A) + (a0+a1)*b1)
    gemm_f32in_kernel<DINF, DHID><<<(N + 31) / 32, 256, 0, stream>>>(feat, W1, A, N);
    agg128_kernel<<<(N + 3) / 4, 256, 0, stream>>>(A, offs, csr, b1, attn, (uint_t*)B, N);

    // layer 2: C = bf16(B @ W2) ; out = agg(C) + (a0+a1)*b2  (f32)
    gemm_b16in_kernel<DHID, DOUTF><<<(N + 63) / 64, 256, 0, stream>>>(B, W2, C, N);
    agg64_kernel<<<(N + 3) / 4, 256, 0, stream>>>(C, offs, csr, b2, attn, out, N);
}

// Round 6
// 234.849 us; speedup vs baseline: 4.3822x; 1.2422x over previous
//
#include <hip/hip_runtime.h>

#define DINF 128
#define DHID 128
#define DOUTF 64

#define CHUNK 12544   // histogram slots per LDS chunk (49 KB)
#define NCHUNK 4      // ceil(50000 / 12544)
#define ECH 16        // edge slices

typedef unsigned short ushort_t;
typedef unsigned int uint_t;
typedef __attribute__((ext_vector_type(8))) short bf16x8;
typedef __attribute__((ext_vector_type(4))) float f32x4;

__device__ __forceinline__ ushort_t f2b(float x) {   // f32 -> bf16 RNE
    uint_t u = __float_as_uint(x);
    u += 0x7fffu + ((u >> 16) & 1u);
    return (ushort_t)(u >> 16);
}
__device__ __forceinline__ float b2f_lo(uint_t u) { return __uint_as_float(u << 16); }
__device__ __forceinline__ float b2f_hi(uint_t u) { return __uint_as_float(u & 0xffff0000u); }

// ---- LDS-privatized degree histogram for all 4 index arrays ----
__global__ void deg_priv_kernel(const int* __restrict__ s1, const int* __restrict__ d1,
                                const int* __restrict__ s2, const int* __restrict__ d2,
                                int* __restrict__ deg, int N, int ne) {
    extern __shared__ int h[];
    int t = threadIdx.x;
    for (int j = t; j < CHUNK; j += 1024) h[j] = 0;
    __syncthreads();

    const int* p = blockIdx.z == 0 ? s1 : blockIdx.z == 1 ? d1 : blockIdx.z == 2 ? s2 : d2;
    int lo = blockIdx.y * CHUNK;
    int per = (ne + ECH - 1) / ECH;
    int e0 = blockIdx.x * per;
    int e1 = e0 + per < ne ? e0 + per : ne;
    for (int i = e0 + t; i < e1; i += 1024) {
        int idx = p[i] - lo;
        if ((unsigned)idx < (unsigned)CHUNK) atomicAdd(&h[idx], 1);
    }
    __syncthreads();

    int* dz = deg + (size_t)blockIdx.z * N;
    for (int j = t; j < CHUNK; j += 1024) {
        int node = lo + j;
        int v = h[j];
        if (v && node < N) atomicAdd(&dz[node], v);
    }
}

// ---- scan phase 1 ----
__global__ void scan1_kernel(const int* __restrict__ d1i, const int* __restrict__ d2i,
                             int* __restrict__ offs, int* __restrict__ bsum, int n) {
    __shared__ int warp_sums[4];
    int t = threadIdx.x;
    int lane = t & 63;
    int wid = t >> 6;
    int base = blockIdx.x * 1024 + t * 4;

    int v[4];
    int tot = 0;
    #pragma unroll
    for (int j = 0; j < 4; ++j) {
        int i = base + j;
        int d = (i < n) ? d1i[i] + d2i[i] : 0;
        v[j] = d; tot += d;
    }
    int x = tot;
    #pragma unroll
    for (int off = 1; off < 64; off <<= 1) {
        int y = __shfl_up(x, off, 64);
        if (lane >= off) x += y;
    }
    if (lane == 63) warp_sums[wid] = x;
    __syncthreads();
    int wbase = 0;
    for (int w = 0; w < wid; ++w) wbase += warp_sums[w];
    int run = wbase + x - tot;
    #pragma unroll
    for (int j = 0; j < 4; ++j) {
        int i = base + j;
        if (i < n) offs[i] = run;
        run += v[j];
    }
    if (t == 255) bsum[blockIdx.x] = run;
}

// ---- scan phase 2 ----
__global__ void scan2_kernel(int* __restrict__ bsum, int* __restrict__ offs, int nb, int n) {
    int lane = threadIdx.x;
    int run = 0;
    for (int base = 0; base < nb; base += 64) {
        int i = base + lane;
        int v = (i < nb) ? bsum[i] : 0;
        int x = v;
        #pragma unroll
        for (int off = 1; off < 64; off <<= 1) {
            int y = __shfl_up(x, off, 64);
            if (lane >= off) x += y;
        }
        if (i < nb) bsum[i] = run + x - v;
        run += __shfl(x, 63, 64);
    }
    if (lane == 0) offs[n] = run;
}

// ---- scan phase 3 ----
__global__ void scan3_kernel(int* __restrict__ offs, int* __restrict__ cursor,
                             const int* __restrict__ bsum, int n) {
    int base = blockIdx.x * 1024 + threadIdx.x * 4;
    int add = bsum[blockIdx.x];
    #pragma unroll
    for (int j = 0; j < 4; ++j) {
        int i = base + j;
        if (i < n) { int o = offs[i] + add; offs[i] = o; cursor[i] = o; }
    }
}

// ---- CSR fill ----
__global__ void fill_kernel(const int* __restrict__ src, const int* __restrict__ dst,
                            const int* __restrict__ deg_out, const int* __restrict__ deg_in,
                            const float* __restrict__ attn, int ai,
                            int* __restrict__ cursor, int2* __restrict__ csr, int ne) {
    int i = blockIdx.x * 256 + threadIdx.x;
    if (i >= ne) return;
    int s = src[i];
    int d = dst[i];
    int pos = atomicAdd(&cursor[d], 1);
    float w = attn[ai] * rsqrtf(fmaxf((float)deg_in[d], 1.0f))
                       * rsqrtf(fmaxf((float)deg_out[s], 1.0f));
    csr[pos] = make_int2(s, __float_as_int(w));
}

// ---- W convert+transpose: Wt[n][k] = bf16(W[k][n]) ----
__global__ void wconv_kernel(const float* __restrict__ W, ushort_t* __restrict__ Wt,
                             int K, int Nc) {
    int tid = blockIdx.x * 256 + threadIdx.x;
    if (tid >= K * Nc) return;
    int ncol = tid / K, k = tid % K;
    Wt[tid] = f2b(W[(size_t)k * Nc + ncol]);
}

// ---- MFMA GEMM: Y[n,NOUT](bf16) = X[n,128] @ W  (Wt = bf16 W^T [NOUT][128]) ----
// block 256 = 4 waves; wave owns 16 rows; no LDS.
template<int NOUT, bool F32IN>
__global__ __launch_bounds__(256) void mfma_gemm_kernel(const void* __restrict__ Xv,
                                                        const ushort_t* __restrict__ Wt,
                                                        ushort_t* __restrict__ Y, int n) {
    constexpr int CT = NOUT / 16;
    const int lane = threadIdx.x & 63;
    const int wv = threadIdx.x >> 6;
    const int row0 = blockIdx.x * 64 + wv * 16;
    const int arow = row0 + (lane & 15);
    const int arc = arow < n ? arow : (n - 1);   // clamp for loads

    f32x4 acc[CT];
    #pragma unroll
    for (int ct = 0; ct < CT; ++ct) acc[ct] = (f32x4)(0.f);

    #pragma unroll
    for (int kk = 0; kk < 4; ++kk) {
        const int k0 = kk * 32 + (lane >> 4) * 8;
        bf16x8 a;
        if (F32IN) {
            const float* xp = (const float*)Xv + (size_t)arc * 128 + k0;
            float4 u0 = *(const float4*)xp;
            float4 u1 = *(const float4*)(xp + 4);
            a[0] = (short)f2b(u0.x); a[1] = (short)f2b(u0.y);
            a[2] = (short)f2b(u0.z); a[3] = (short)f2b(u0.w);
            a[4] = (short)f2b(u1.x); a[5] = (short)f2b(u1.y);
            a[6] = (short)f2b(u1.z); a[7] = (short)f2b(u1.w);
        } else {
            a = *(const bf16x8*)((const ushort_t*)Xv + (size_t)arc * 128 + k0);
        }
        #pragma unroll
        for (int ct = 0; ct < CT; ++ct) {
            bf16x8 b = *(const bf16x8*)(Wt + (size_t)(ct * 16 + (lane & 15)) * 128 + k0);
            acc[ct] = __builtin_amdgcn_mfma_f32_16x16x32_bf16(a, b, acc[ct], 0, 0, 0);
        }
    }

    const int orow0 = row0 + (lane >> 4) * 4;
    const int col = lane & 15;
    #pragma unroll
    for (int ct = 0; ct < CT; ++ct) {
        #pragma unroll
        for (int r = 0; r < 4; ++r) {
            int row = orow0 + r;
            if (row < n) Y[(size_t)row * NOUT + ct * 16 + col] = f2b(acc[ct][r]);
        }
    }
}

// ---- agg D=128: gather bf16 rows (uint = 2 bf16 per lane), write bf16 x1 ----
__global__ void agg128_kernel(const ushort_t* __restrict__ V, const int* __restrict__ offs,
                              const int2* __restrict__ csr, const float* __restrict__ bias,
                              const float* __restrict__ attn, uint_t* __restrict__ out, int n) {
    int wid = (int)(((size_t)blockIdx.x * blockDim.x + threadIdx.x) >> 6);
    int lane = threadIdx.x & 63;
    if (wid >= n) return;
    int e0 = offs[wid], e1 = offs[wid + 1];

    float acc0 = 0.f, acc1 = 0.f;

    int e = e0;
    for (; e + 4 <= e1; e += 4) {
        int2 c0v = csr[e + 0], c1v = csr[e + 1], c2v = csr[e + 2], c3v = csr[e + 3];
        float w0 = __int_as_float(c0v.y), w1 = __int_as_float(c1v.y);
        float w2 = __int_as_float(c2v.y), w3 = __int_as_float(c3v.y);
        uint_t u0 = ((const uint_t*)(V + (size_t)c0v.x * 128))[lane];
        uint_t u1 = ((const uint_t*)(V + (size_t)c1v.x * 128))[lane];
        uint_t u2 = ((const uint_t*)(V + (size_t)c2v.x * 128))[lane];
        uint_t u3 = ((const uint_t*)(V + (size_t)c3v.x * 128))[lane];
        acc0 += w0 * b2f_lo(u0); acc1 += w0 * b2f_hi(u0);
        acc0 += w1 * b2f_lo(u1); acc1 += w1 * b2f_hi(u1);
        acc0 += w2 * b2f_lo(u2); acc1 += w2 * b2f_hi(u2);
        acc0 += w3 * b2f_lo(u3); acc1 += w3 * b2f_hi(u3);
    }
    for (; e < e1; ++e) {
        int2 cv = csr[e];
        float w = __int_as_float(cv.y);
        uint_t u = ((const uint_t*)(V + (size_t)cv.x * 128))[lane];
        acc0 += w * b2f_lo(u); acc1 += w * b2f_hi(u);
    }

    float bs = attn[0] + attn[1];
    float2 bb = ((const float2*)bias)[lane];
    float o0 = acc0 + bs * bb.x;
    float o1 = acc1 + bs * bb.y;
    out[(size_t)wid * 64 + lane] = (uint_t)f2b(o0) | ((uint_t)f2b(o1) << 16);
}

// ---- agg D=64: gather bf16 rows (ushort per lane), write f32 output ----
__global__ void agg64_kernel(const ushort_t* __restrict__ V, const int* __restrict__ offs,
                             const int2* __restrict__ csr, const float* __restrict__ bias,
                             const float* __restrict__ attn, float* __restrict__ out, int n) {
    int wid = (int)(((size_t)blockIdx.x * blockDim.x + threadIdx.x) >> 6);
    int lane = threadIdx.x & 63;
    if (wid >= n) return;
    int e0 = offs[wid], e1 = offs[wid + 1];

    float acc = 0.f;

    int e = e0;
    for (; e + 4 <= e1; e += 4) {
        int2 c0v = csr[e + 0], c1v = csr[e + 1], c2v = csr[e + 2], c3v = csr[e + 3];
        float w0 = __int_as_float(c0v.y), w1 = __int_as_float(c1v.y);
        float w2 = __int_as_float(c2v.y), w3 = __int_as_float(c3v.y);
        float g0 = __uint_as_float(((uint_t)V[(size_t)c0v.x * 64 + lane]) << 16);
        float g1 = __uint_as_float(((uint_t)V[(size_t)c1v.x * 64 + lane]) << 16);
        float g2 = __uint_as_float(((uint_t)V[(size_t)c2v.x * 64 + lane]) << 16);
        float g3 = __uint_as_float(((uint_t)V[(size_t)c3v.x * 64 + lane]) << 16);
        acc += w0 * g0 + w1 * g1 + w2 * g2 + w3 * g3;
    }
    for (; e < e1; ++e) {
        int2 cv = csr[e];
        float w = __int_as_float(cv.y);
        float g = __uint_as_float(((uint_t)V[(size_t)cv.x * 64 + lane]) << 16);
        acc += w * g;
    }

    float bs = attn[0] + attn[1];
    out[(size_t)wid * 64 + lane] = acc + bs * bias[lane];
}

extern "C" void kernel_launch(void* const* d_in, const int* in_sizes, int n_in,
                              void* d_out, int out_size, void* d_ws, size_t ws_size,
                              hipStream_t stream) {
    const float* feat = (const float*)d_in[0];
    const int* src1   = (const int*)d_in[1];
    const int* dst1   = (const int*)d_in[2];
    const int* src2   = (const int*)d_in[3];
    const int* dst2   = (const int*)d_in[4];
    const float* attn = (const float*)d_in[5];
    const float* W1   = (const float*)d_in[6];
    const float* b1   = (const float*)d_in[7];
    const float* W2   = (const float*)d_in[8];
    const float* b2   = (const float*)d_in[9];
    float* out = (float*)d_out;

    const int N  = in_sizes[0] / DINF;   // 50000
    const int NE = in_sizes[1];          // 600000
    const int NB = (N + 1023) / 1024;    // scan blocks

    // workspace layout (bf16 buffers first, all 16B-aligned):
    // Wt1[128*128] bf16 | Wt2[64*128] bf16 | A bf16[N*128] | B bf16[N*128] |
    // C bf16[N*64] | csr int2[2*NE] | offs[N+1] | cursor[N] | deg[4*N] | bsum[NB]
    ushort_t* Wt1 = (ushort_t*)d_ws;
    ushort_t* Wt2 = Wt1 + 128 * 128;
    ushort_t* A   = Wt2 + 64 * 128;
    ushort_t* B   = A + (size_t)N * DHID;
    ushort_t* C   = B + (size_t)N * DHID;
    int2* csr   = (int2*)(C + (size_t)N * DOUTF);
    int* offs   = (int*)(csr + 2 * (size_t)NE);
    int* cursor = offs + (N + 1);
    int* deg    = cursor + N;
    int* d1o = deg;
    int* d1i = deg + N;
    int* d2o = deg + 2 * (size_t)N;
    int* d2i = deg + 3 * (size_t)N;
    int* bsum = deg + 4 * (size_t)N;

    hipMemsetAsync(deg, 0, sizeof(int) * 4 * (size_t)N, stream);

    // weight transpose+convert (independent of everything else)
    wconv_kernel<<<(128 * 128 + 255) / 256, 256, 0, stream>>>(W1, Wt1, 128, 128);
    wconv_kernel<<<(128 * 64 + 255) / 256, 256, 0, stream>>>(W2, Wt2, 128, 64);

    deg_priv_kernel<<<dim3(ECH, NCHUNK, 4), 1024, CHUNK * sizeof(int), stream>>>(
        src1, dst1, src2, dst2, deg, N, NE);

    scan1_kernel<<<NB, 256, 0, stream>>>(d1i, d2i, offs, bsum, N);
    scan2_kernel<<<1, 64, 0, stream>>>(bsum, offs, NB, N);
    scan3_kernel<<<NB, 256, 0, stream>>>(offs, cursor, bsum, N);

    int eb = (NE + 255) / 256;
    fill_kernel<<<eb, 256, 0, stream>>>(src1, dst1, d1o, d1i, attn, 0, cursor, csr, NE);
    fill_kernel<<<eb, 256, 0, stream>>>(src2, dst2, d2o, d2i, attn, 1, cursor, csr, NE);

    int gb = (N + 63) / 64;
    // layer 1: A = bf16(feat @ W1) ; B = bf16(agg(A) + (a0+a1)*b1)
    mfma_gemm_kernel<DHID, true><<<gb, 256, 0, stream>>>(feat, Wt1, A, N);
    agg128_kernel<<<(N + 3) / 4, 256, 0, stream>>>(A, offs, csr, b1, attn, (uint_t*)B, N);

    // layer 2: C = bf16(B @ W2) ; out = agg(C) + (a0+a1)*b2  (f32)
    mfma_gemm_kernel<DOUTF, false><<<gb, 256, 0, stream>>>(B, Wt2, C, N);
    agg64_kernel<<<(N + 3) / 4, 256, 0, stream>>>(C, offs, csr, b2, attn, out, N);
}

// Round 7
// 212.903 us; speedup vs baseline: 4.8340x; 1.1031x over previous
//
#include <hip/hip_runtime.h>

#define DINF 128
#define DHID 128
#define DOUTF 64

#define CHUNK 12544   // histogram slots per LDS chunk (49 KB)
#define NCHUNK 4      // ceil(50000 / 12544)
#define ECH 16        // edge slices

typedef unsigned short ushort_t;
typedef unsigned int uint_t;
typedef __attribute__((ext_vector_type(8))) short bf16x8;
typedef __attribute__((ext_vector_type(4))) float f32x4;

__device__ __forceinline__ ushort_t f2b(float x) {   // f32 -> bf16 RNE
    uint_t u = __float_as_uint(x);
    u += 0x7fffu + ((u >> 16) & 1u);
    return (ushort_t)(u >> 16);
}
__device__ __forceinline__ float b2f_lo(uint_t u) { return __uint_as_float(u << 16); }
__device__ __forceinline__ float b2f_hi(uint_t u) { return __uint_as_float(u & 0xffff0000u); }

// ---- LDS-privatized degree histogram for all 4 index arrays ----
__global__ void deg_priv_kernel(const int* __restrict__ s1, const int* __restrict__ d1,
                                const int* __restrict__ s2, const int* __restrict__ d2,
                                int* __restrict__ deg, int N, int ne) {
    extern __shared__ int h[];
    int t = threadIdx.x;
    for (int j = t; j < CHUNK; j += 1024) h[j] = 0;
    __syncthreads();

    const int* p = blockIdx.z == 0 ? s1 : blockIdx.z == 1 ? d1 : blockIdx.z == 2 ? s2 : d2;
    int lo = blockIdx.y * CHUNK;
    int per = (ne + ECH - 1) / ECH;
    int e0 = blockIdx.x * per;
    int e1 = e0 + per < ne ? e0 + per : ne;
    for (int i = e0 + t; i < e1; i += 1024) {
        int idx = p[i] - lo;
        if ((unsigned)idx < (unsigned)CHUNK) atomicAdd(&h[idx], 1);
    }
    __syncthreads();

    int* dz = deg + (size_t)blockIdx.z * N;
    for (int j = t; j < CHUNK; j += 1024) {
        int node = lo + j;
        int v = h[j];
        if (v && node < N) atomicAdd(&dz[node], v);
    }
}

// ---- scan phase 1 ----
__global__ void scan1_kernel(const int* __restrict__ d1i, const int* __restrict__ d2i,
                             int* __restrict__ offs, int* __restrict__ bsum, int n) {
    __shared__ int warp_sums[4];
    int t = threadIdx.x;
    int lane = t & 63;
    int wid = t >> 6;
    int base = blockIdx.x * 1024 + t * 4;

    int v[4];
    int tot = 0;
    #pragma unroll
    for (int j = 0; j < 4; ++j) {
        int i = base + j;
        int d = (i < n) ? d1i[i] + d2i[i] : 0;
        v[j] = d; tot += d;
    }
    int x = tot;
    #pragma unroll
    for (int off = 1; off < 64; off <<= 1) {
        int y = __shfl_up(x, off, 64);
        if (lane >= off) x += y;
    }
    if (lane == 63) warp_sums[wid] = x;
    __syncthreads();
    int wbase = 0;
    for (int w = 0; w < wid; ++w) wbase += warp_sums[w];
    int run = wbase + x - tot;
    #pragma unroll
    for (int j = 0; j < 4; ++j) {
        int i = base + j;
        if (i < n) offs[i] = run;
        run += v[j];
    }
    if (t == 255) bsum[blockIdx.x] = run;
}

// ---- scan phase 2 ----
__global__ void scan2_kernel(int* __restrict__ bsum, int* __restrict__ offs, int nb, int n) {
    int lane = threadIdx.x;
    int run = 0;
    for (int base = 0; base < nb; base += 64) {
        int i = base + lane;
        int v = (i < nb) ? bsum[i] : 0;
        int x = v;
        #pragma unroll
        for (int off = 1; off < 64; off <<= 1) {
            int y = __shfl_up(x, off, 64);
            if (lane >= off) x += y;
        }
        if (i < nb) bsum[i] = run + x - v;
        run += __shfl(x, 63, 64);
    }
    if (lane == 0) offs[n] = run;
}

// ---- scan phase 3 ----
__global__ void scan3_kernel(int* __restrict__ offs, int* __restrict__ cursor,
                             const int* __restrict__ bsum, int n) {
    int base = blockIdx.x * 1024 + threadIdx.x * 4;
    int add = bsum[blockIdx.x];
    #pragma unroll
    for (int j = 0; j < 4; ++j) {
        int i = base + j;
        if (i < n) { int o = offs[i] + add; offs[i] = o; cursor[i] = o; }
    }
}

// ---- CSR fill (both graphs; blockIdx.y selects) ----
__global__ void fill2_kernel(const int* __restrict__ src1, const int* __restrict__ dst1,
                             const int* __restrict__ src2, const int* __restrict__ dst2,
                             const int* __restrict__ deg, const float* __restrict__ attn,
                             int* __restrict__ cursor, int2* __restrict__ csr, int N, int ne) {
    int i = blockIdx.x * 256 + threadIdx.x;
    if (i >= ne) return;
    int g = blockIdx.y;
    const int* src = g == 0 ? src1 : src2;
    const int* dst = g == 0 ? dst1 : dst2;
    const int* deg_out = deg + (size_t)(2 * g) * N;
    const int* deg_in  = deg + (size_t)(2 * g + 1) * N;
    int s = src[i];
    int d = dst[i];
    int pos = atomicAdd(&cursor[d], 1);
    float w = attn[g] * rsqrtf(fmaxf((float)deg_in[d], 1.0f))
                      * rsqrtf(fmaxf((float)deg_out[s], 1.0f));
    csr[pos] = make_int2(s, __float_as_int(w));
}

// ---- W convert+transpose, both weights in one launch ----
__global__ void wconv2_kernel(const float* __restrict__ W1, const float* __restrict__ W2,
                              ushort_t* __restrict__ Wt1, ushort_t* __restrict__ Wt2) {
    int tid = blockIdx.x * 256 + threadIdx.x;
    if (tid < 128 * 128) {
        int ncol = tid / 128, k = tid % 128;
        Wt1[tid] = f2b(W1[(size_t)k * 128 + ncol]);
    } else if (tid < 128 * 128 + 64 * 128) {
        int t2 = tid - 128 * 128;
        int ncol = t2 / 128, k = t2 % 128;
        Wt2[t2] = f2b(W2[(size_t)k * 64 + ncol]);
    }
}

// ---- MFMA GEMM: Y[n,NOUT](bf16) = X[n,128] @ W  (Wt = bf16 W^T [NOUT][128]) ----
template<int NOUT, bool F32IN>
__global__ __launch_bounds__(256) void mfma_gemm_kernel(const void* __restrict__ Xv,
                                                        const ushort_t* __restrict__ Wt,
                                                        ushort_t* __restrict__ Y, int n) {
    constexpr int CT = NOUT / 16;
    const int lane = threadIdx.x & 63;
    const int wv = threadIdx.x >> 6;
    const int row0 = blockIdx.x * 64 + wv * 16;
    const int arow = row0 + (lane & 15);
    const int arc = arow < n ? arow : (n - 1);   // clamp for loads

    f32x4 acc[CT];
    #pragma unroll
    for (int ct = 0; ct < CT; ++ct) acc[ct] = (f32x4)(0.f);

    #pragma unroll
    for (int kk = 0; kk < 4; ++kk) {
        const int k0 = kk * 32 + (lane >> 4) * 8;
        bf16x8 a;
        if (F32IN) {
            const float* xp = (const float*)Xv + (size_t)arc * 128 + k0;
            float4 u0 = *(const float4*)xp;
            float4 u1 = *(const float4*)(xp + 4);
            a[0] = (short)f2b(u0.x); a[1] = (short)f2b(u0.y);
            a[2] = (short)f2b(u0.z); a[3] = (short)f2b(u0.w);
            a[4] = (short)f2b(u1.x); a[5] = (short)f2b(u1.y);
            a[6] = (short)f2b(u1.z); a[7] = (short)f2b(u1.w);
        } else {
            a = *(const bf16x8*)((const ushort_t*)Xv + (size_t)arc * 128 + k0);
        }
        #pragma unroll
        for (int ct = 0; ct < CT; ++ct) {
            bf16x8 b = *(const bf16x8*)(Wt + (size_t)(ct * 16 + (lane & 15)) * 128 + k0);
            acc[ct] = __builtin_amdgcn_mfma_f32_16x16x32_bf16(a, b, acc[ct], 0, 0, 0);
        }
    }

    const int orow0 = row0 + (lane >> 4) * 4;
    const int col = lane & 15;
    #pragma unroll
    for (int ct = 0; ct < CT; ++ct) {
        #pragma unroll
        for (int r = 0; r < 4; ++r) {
            int row = orow0 + r;
            if (row < n) Y[(size_t)row * NOUT + ct * 16 + col] = f2b(acc[ct][r]);
        }
    }
}

// ---- agg D=128: 8 gathers in flight per wave; uint (2 bf16) per lane ----
__global__ void agg128_kernel(const ushort_t* __restrict__ V, const int* __restrict__ offs,
                              const int2* __restrict__ csr, const float* __restrict__ bias,
                              const float* __restrict__ attn, uint_t* __restrict__ out, int n) {
    int wid = (int)(((size_t)blockIdx.x * blockDim.x + threadIdx.x) >> 6);
    int lane = threadIdx.x & 63;
    if (wid >= n) return;
    int e0 = offs[wid], e1 = offs[wid + 1];

    float acc0 = 0.f, acc1 = 0.f;

    int e = e0;
    for (; e + 8 <= e1; e += 8) {
        int2 cv[8];
        uint_t u[8];
        #pragma unroll
        for (int j = 0; j < 8; ++j) cv[j] = csr[e + j];
        #pragma unroll
        for (int j = 0; j < 8; ++j)
            u[j] = ((const uint_t*)(V + (size_t)cv[j].x * 128))[lane];
        #pragma unroll
        for (int j = 0; j < 8; ++j) {
            float w = __int_as_float(cv[j].y);
            acc0 += w * b2f_lo(u[j]);
            acc1 += w * b2f_hi(u[j]);
        }
    }
    if (e + 4 <= e1) {
        int2 cv[4];
        uint_t u[4];
        #pragma unroll
        for (int j = 0; j < 4; ++j) cv[j] = csr[e + j];
        #pragma unroll
        for (int j = 0; j < 4; ++j)
            u[j] = ((const uint_t*)(V + (size_t)cv[j].x * 128))[lane];
        #pragma unroll
        for (int j = 0; j < 4; ++j) {
            float w = __int_as_float(cv[j].y);
            acc0 += w * b2f_lo(u[j]);
            acc1 += w * b2f_hi(u[j]);
        }
        e += 4;
    }
    for (; e < e1; ++e) {
        int2 cv = csr[e];
        float w = __int_as_float(cv.y);
        uint_t u = ((const uint_t*)(V + (size_t)cv.x * 128))[lane];
        acc0 += w * b2f_lo(u); acc1 += w * b2f_hi(u);
    }

    float bs = attn[0] + attn[1];
    float2 bb = ((const float2*)bias)[lane];
    float o0 = acc0 + bs * bb.x;
    float o1 = acc1 + bs * bb.y;
    out[(size_t)wid * 64 + lane] = (uint_t)f2b(o0) | ((uint_t)f2b(o1) << 16);
}

// ---- agg D=64: half-wave per edge (32 lanes x 4B = full 128B row), 8 in flight ----
__global__ void agg64_kernel(const ushort_t* __restrict__ V, const int* __restrict__ offs,
                             const int2* __restrict__ csr, const float* __restrict__ bias,
                             const float* __restrict__ attn, float* __restrict__ out, int n) {
    int wid = (int)(((size_t)blockIdx.x * blockDim.x + threadIdx.x) >> 6);
    int lane = threadIdx.x & 63;
    int half = lane >> 5;       // 0 or 1
    int hl = lane & 31;         // lane within half
    if (wid >= n) return;
    int e0 = offs[wid], e1 = offs[wid + 1];

    float acc0 = 0.f, acc1 = 0.f;   // cols 2*hl, 2*hl+1

    int e = e0;
    for (; e + 8 <= e1; e += 8) {
        int2 cv[4];
        uint_t u[4];
        #pragma unroll
        for (int j = 0; j < 4; ++j) cv[j] = csr[e + 2 * j + half];
        #pragma unroll
        for (int j = 0; j < 4; ++j)
            u[j] = ((const uint_t*)(V + (size_t)cv[j].x * 64))[hl];
        #pragma unroll
        for (int j = 0; j < 4; ++j) {
            float w = __int_as_float(cv[j].y);
            acc0 += w * b2f_lo(u[j]);
            acc1 += w * b2f_hi(u[j]);
        }
    }
    for (; e + 2 <= e1; e += 2) {
        int2 cv = csr[e + half];
        float w = __int_as_float(cv.y);
        uint_t u = ((const uint_t*)(V + (size_t)cv.x * 64))[hl];
        acc0 += w * b2f_lo(u); acc1 += w * b2f_hi(u);
    }
    if (e < e1 && half == 0) {   // odd leftover: half 0 only
        int2 cv = csr[e];
        float w = __int_as_float(cv.y);
        uint_t u = ((const uint_t*)(V + (size_t)cv.x * 64))[hl];
        acc0 += w * b2f_lo(u); acc1 += w * b2f_hi(u);
    }

    // combine the two half-wave partial sums
    acc0 += __shfl_xor(acc0, 32, 64);
    acc1 += __shfl_xor(acc1, 32, 64);

    if (half == 0) {
        float bs = attn[0] + attn[1];
        float2 bb = ((const float2*)bias)[hl];
        float2 o = make_float2(acc0 + bs * bb.x, acc1 + bs * bb.y);
        ((float2*)(out + (size_t)wid * 64))[hl] = o;
    }
}

extern "C" void kernel_launch(void* const* d_in, const int* in_sizes, int n_in,
                              void* d_out, int out_size, void* d_ws, size_t ws_size,
                              hipStream_t stream) {
    const float* feat = (const float*)d_in[0];
    const int* src1   = (const int*)d_in[1];
    const int* dst1   = (const int*)d_in[2];
    const int* src2   = (const int*)d_in[3];
    const int* dst2   = (const int*)d_in[4];
    const float* attn = (const float*)d_in[5];
    const float* W1   = (const float*)d_in[6];
    const float* b1   = (const float*)d_in[7];
    const float* W2   = (const float*)d_in[8];
    const float* b2   = (const float*)d_in[9];
    float* out = (float*)d_out;

    const int N  = in_sizes[0] / DINF;   // 50000
    const int NE = in_sizes[1];          // 600000
    const int NB = (N + 1023) / 1024;    // scan blocks

    // workspace layout (bf16 buffers first, all 16B-aligned):
    // Wt1[128*128] bf16 | Wt2[64*128] bf16 | A bf16[N*128] | B bf16[N*128] |
    // C bf16[N*64] | csr int2[2*NE] | offs[N+1] | cursor[N] | deg[4*N] | bsum[NB]
    ushort_t* Wt1 = (ushort_t*)d_ws;
    ushort_t* Wt2 = Wt1 + 128 * 128;
    ushort_t* A   = Wt2 + 64 * 128;
    ushort_t* B   = A + (size_t)N * DHID;
    ushort_t* C   = B + (size_t)N * DHID;
    int2* csr   = (int2*)(C + (size_t)N * DOUTF);
    int* offs   = (int*)(csr + 2 * (size_t)NE);
    int* cursor = offs + (N + 1);
    int* deg    = cursor + N;
    int* d1i = deg + N;
    int* d2i = deg + 3 * (size_t)N;
    int* bsum = deg + 4 * (size_t)N;

    hipMemsetAsync(deg, 0, sizeof(int) * 4 * (size_t)N, stream);

    wconv2_kernel<<<(128 * 128 + 64 * 128 + 255) / 256, 256, 0, stream>>>(W1, W2, Wt1, Wt2);

    deg_priv_kernel<<<dim3(ECH, NCHUNK, 4), 1024, CHUNK * sizeof(int), stream>>>(
        src1, dst1, src2, dst2, deg, N, NE);

    scan1_kernel<<<NB, 256, 0, stream>>>(d1i, d2i, offs, bsum, N);
    scan2_kernel<<<1, 64, 0, stream>>>(bsum, offs, NB, N);
    scan3_kernel<<<NB, 256, 0, stream>>>(offs, cursor, bsum, N);

    int eb = (NE + 255) / 256;
    fill2_kernel<<<dim3(eb, 2), 256, 0, stream>>>(src1, dst1, src2, dst2, deg, attn,
                                                  cursor, csr, N, NE);

    int gb = (N + 63) / 64;
    // layer 1: A = bf16(feat @ W1) ; B = bf16(agg(A) + (a0+a1)*b1)
    mfma_gemm_kernel<DHID, true><<<gb, 256, 0, stream>>>(feat, Wt1, A, N);
    agg128_kernel<<<(N + 3) / 4, 256, 0, stream>>>(A, offs, csr, b1, attn, (uint_t*)B, N);

    // layer 2: C = bf16(B @ W2) ; out = agg(C) + (a0+a1)*b2  (f32)
    mfma_gemm_kernel<DOUTF, false><<<gb, 256, 0, stream>>>(B, Wt2, C, N);
    agg64_kernel<<<(N + 3) / 4, 256, 0, stream>>>(C, offs, csr, b2, attn, out, N);
}